// Round 15
// baseline (61.605 us; speedup 1.0000x reference)
//
#include <hip/hip_runtime.h>
#include <math.h>

#define B_   8
#define L_   4
#define P_   1024
#define C_   256
#define NH_  8
#define NS_  4
#define HD_  32

typedef _Float16 half8 __attribute__((ext_vector_type(8)));
typedef _Float16 half4 __attribute__((ext_vector_type(4)));
typedef float    f32x4 __attribute__((ext_vector_type(4)));

// ws layout (float offsets)
#define G_F     0u          // projected maps fp16: 1,392,640 halves
#define SAMP_F  1392640u    // per-sample (w,fx,fy,0) float4: 32768*32*4 floats
#define WU_F    5586944u    // WuT fp16 (96,256): 12288 halves
#define ET_F    5611520u    // embed_w fp16 e-major (4,32,256): 32768 halves

__constant__ const int kGoff[4] = {0, 1048576, 1310720, 1376256};  // half units

#define LGS 100             // logits row stride (floats)
#define NG_GPROJ 680        // 8 batches * 85 tiles

// ---------------------------------------------------------------------------
// k0: WuT fp16 (96,256) K-major  +  ET16 fp16 (4,32,256) e-major
// ---------------------------------------------------------------------------
__global__ void k0_conv(const float* __restrict__ wa, const float* __restrict__ wo,
                        const float* __restrict__ embed_w,
                        _Float16* __restrict__ WuT, _Float16* __restrict__ ET16) {
  const int bx = blockIdx.x, t = threadIdx.x;
  if (bx < 96) {
    const int n = bx;
    const float v = (n < 32) ? wa[t * 32 + n] : wo[t * 64 + (n - 32)];
    WuT[n * 256 + t] = (_Float16)v;
  } else {
    // embed: 32 blocks x 256 t x 4 elems; src (l, c, 32e), dst (l, e, 256c)
    const int i0 = (bx - 96) * 1024 + t * 4;
    const int l = i0 >> 13, rem = i0 & 8191;
    const int c = rem >> 5, e0 = rem & 31;
    const float4 v = *(const float4*)(embed_w + i0);
    _Float16* d = ET16 + l * 8192 + c;
    d[(e0 + 0) * 256] = (_Float16)v.x;
    d[(e0 + 1) * 256] = (_Float16)v.y;
    d[(e0 + 2) * 256] = (_Float16)v.z;
    d[(e0 + 3) * 256] = (_Float16)v.w;
  }
}

// ---------------------------------------------------------------------------
// stage1: horizontal fusion, BARRIER-FREE compute in both paths.
//   blocks [0, 680):   gproj via MFMA, A-frags gathered direct from feat
//                      (no LDS), B-frags from L2-hot ET16. Zero barriers.
//   blocks [680,1192): k2 register MFMA GEMM (A direct from x, B from WuT),
//                      one barrier pair only for the lg epilogue.
// ---------------------------------------------------------------------------
__global__ __launch_bounds__(256) void stage1(
    const float* __restrict__ f0, const float* __restrict__ f1,
    const float* __restrict__ f2, const float* __restrict__ f3,
    const _Float16* __restrict__ ET16, _Float16* __restrict__ g16,
    const float* __restrict__ x,    // (32768, 256)
    const float* __restrict__ ref,  // (32768, 2)
    const _Float16* __restrict__ WuT,
    const float* __restrict__ ba, const float* __restrict__ bo,
    float4* __restrict__ samp4)     // (32768, 32)
{
  __shared__ float lg[64 * LGS];    // 25600 B (k2 epilogue only)
  const int t = threadIdx.x;
  const int bx = blockIdx.x;
  const int lane = t & 63, wv = t >> 6;
  const int lr = lane & 15, kg = lane >> 4;

  if (bx < NG_GPROJ) {
    // ========== gproj path: no LDS, no barriers ==========
    const int b = bx / 85;
    int sub = bx - b * 85, l, tile;
    const float* src;
    if (sub < 64)      { l = 0; tile = sub;      src = f0; }
    else if (sub < 80) { l = 1; tile = sub - 64; src = f1; }
    else if (sub < 84) { l = 2; tile = sub - 80; src = f2; }
    else               { l = 3; tile = 0;        src = f3; }
    const int Wl = 64 >> l, S = Wl * Wl;
    const int s0 = tile * 64;
    const int srow = s0 + wv * 16 + lr;          // this lane's M row

    const float* sb = src + (size_t)b * C_ * S + srow;  // + c*S walks channels
    const _Float16* ETl = ET16 + (size_t)l * 8192;

    f32x4 acc0 = (f32x4){0.f, 0.f, 0.f, 0.f};
    f32x4 acc1 = (f32x4){0.f, 0.f, 0.f, 0.f};

    float vc[8], vn[8];
    #pragma unroll
    for (int i = 0; i < 8; ++i) vn[i] = sb[(size_t)(kg * 8 + i) * S];

    #pragma unroll
    for (int c = 0; c < 8; ++c) {
      const int c0 = c * 32;
      #pragma unroll
      for (int i = 0; i < 8; ++i) vc[i] = vn[i];
      if (c < 7) {
        #pragma unroll
        for (int i = 0; i < 8; ++i)
          vn[i] = sb[(size_t)(c0 + 32 + kg * 8 + i) * S];
      }
      const half8 a = {(_Float16)vc[0], (_Float16)vc[1], (_Float16)vc[2], (_Float16)vc[3],
                       (_Float16)vc[4], (_Float16)vc[5], (_Float16)vc[6], (_Float16)vc[7]};
      const half8 b0 = *(const half8*)(ETl + (size_t)lr * 256 + c0 + kg * 8);
      const half8 b1 = *(const half8*)(ETl + (size_t)(16 + lr) * 256 + c0 + kg * 8);
      acc0 = __builtin_amdgcn_mfma_f32_16x16x32_f16(a, b0, acc0, 0, 0, 0);
      acc1 = __builtin_amdgcn_mfma_f32_16x16x32_f16(a, b1, acc1, 0, 0, 0);
    }

    // D: row (s_local) = kg*4+r, col (e) = {lr, 16+lr}
    _Float16* gb = g16 + kGoff[l] + ((size_t)b * S + s0 + wv * 16 + kg * 4) * 32;
    #pragma unroll
    for (int r = 0; r < 4; ++r) {
      gb[r * 32 + lr]      = (_Float16)acc0[r];
      gb[r * 32 + 16 + lr] = (_Float16)acc1[r];
    }
    return;
  }

  // ========== k2 path: register GEMM, epilogue-only barriers ==========
  const int blk = bx - NG_GPROJ;                 // 0..511
  const int gp0 = blk * 64;

  // A-fragments: per-lane contiguous 32 B loads direct from x
  const float* xrow = x + (size_t)(gp0 + wv * 16 + lr) * 256;
  half8 af[8];
  #pragma unroll
  for (int f = 0; f < 8; ++f) {
    const float4* p = (const float4*)(xrow + f * 32 + kg * 8);
    const float4 u = p[0], w2 = p[1];
    af[f] = (half8){(_Float16)u.x,  (_Float16)u.y,  (_Float16)u.z,  (_Float16)u.w,
                    (_Float16)w2.x, (_Float16)w2.y, (_Float16)w2.z, (_Float16)w2.w};
  }

  f32x4 acc[6];
  #pragma unroll
  for (int nt = 0; nt < 6; ++nt) acc[nt] = (f32x4){0.f, 0.f, 0.f, 0.f};

  #pragma unroll
  for (int f = 0; f < 8; ++f) {
    const int koff = f * 32 + kg * 8;
    #pragma unroll
    for (int nt = 0; nt < 6; ++nt) {
      const half8 bf = *(const half8*)(WuT + (size_t)(nt * 16 + lr) * 256 + koff);
      acc[nt] = __builtin_amdgcn_mfma_f32_16x16x32_f16(af[f], bf, acc[nt], 0, 0, 0);
    }
  }

  // spill logits (+bias): D col = lane&15 (n), row = kg*4+r (point)
  #pragma unroll
  for (int nt = 0; nt < 6; ++nt) {
    const int n = nt * 16 + lr;
    const float bv = (n < 32) ? ba[n] : bo[n - 32];
    #pragma unroll
    for (int r = 0; r < 4; ++r)
      lg[(wv * 16 + kg * 4 + r) * LGS + n] = acc[nt][r] + bv;
  }
  __syncthreads();

  // softmax + tanh + grid mapping -> samp4
  #pragma unroll
  for (int k = 0; k < 8; ++k) {
    const int slot = k * 256 + t;
    const int pp = slot >> 5, j = slot & 31;
    const int gp = gp0 + pp;
    const int l = (gp >> 10) & 3;
    const int Wl = 64 >> l;
    const float* lgp = lg + pp * LGS;
    const int h4 = (j >> 2) * 4;
    const float l0 = lgp[h4], l1 = lgp[h4 + 1], l2 = lgp[h4 + 2], l3 = lgp[h4 + 3];
    const float m = fmaxf(fmaxf(l0, l1), fmaxf(l2, l3));
    const float e0 = expf(l0 - m), e1 = expf(l1 - m), e2 = expf(l2 - m), e3 = expf(l3 - m);
    const float inv = 1.f / (e0 + e1 + e2 + e3);
    const float es[4] = {e0, e1, e2, e3};
    const float wj = es[j & 3] * inv;
    const float ox = tanhf(lgp[32 + 2 * j])     + ref[(size_t)gp * 2];
    const float oy = tanhf(lgp[32 + 2 * j + 1]) + ref[(size_t)gp * 2 + 1];
    const float sc = 0.5f * (float)(Wl - 1);
    samp4[(size_t)gp * 32 + j] = make_float4(wj, (ox + 1.f) * sc, (oy + 1.f) * sc, 0.f);
  }
}

// ---------------------------------------------------------------------------
// k3: 8 points/block (4096 blocks). Tap precompute -> fp16 gather -> out.
// ---------------------------------------------------------------------------
__global__ __launch_bounds__(256) void k3_main(
    const _Float16* __restrict__ g16,
    const float4* __restrict__ samp4,
    const float* __restrict__ embed_b,   // (L, 32)
    float* __restrict__ out)             // (32768, 256)
{
  __shared__ int4   tofs[256];
  __shared__ float4 tws[256];
  const int t = threadIdx.x, blk = blockIdx.x;   // 4096 blocks
  const int gp0 = blk * 8;
  const int l = (gp0 >> 10) & 3, b = gp0 >> 12;
  const int Wl = 64 >> l;
  const int gbase = kGoff[l] + b * Wl * Wl * 32;  // half units

  {
    const float4 s = samp4[(size_t)gp0 * 32 + t];
    const float fx = s.y, fy = s.z;
    const float x0f = floorf(fx), y0f = floorf(fy);
    const int x0 = (int)x0f, y0 = (int)y0f, x1 = x0 + 1, y1 = y0 + 1;
    const float wx1 = fx - x0f, wy1 = fy - y0f;
    const float wx0 = 1.f - wx1, wy0 = 1.f - wy1;
    const float xv0 = (x0 >= 0 && x0 < Wl) ? 1.f : 0.f;
    const float xv1 = (x1 >= 0 && x1 < Wl) ? 1.f : 0.f;
    const float yv0 = (y0 >= 0 && y0 < Wl) ? 1.f : 0.f;
    const float yv1 = (y1 >= 0 && y1 < Wl) ? 1.f : 0.f;
    const int x0c = min(max(x0, 0), Wl - 1), x1c = min(max(x1, 0), Wl - 1);
    const int y0c = min(max(y0, 0), Wl - 1), y1c = min(max(y1, 0), Wl - 1);
    tofs[t] = make_int4(gbase + (y0c * Wl + x0c) * 32,
                        gbase + (y0c * Wl + x1c) * 32,
                        gbase + (y1c * Wl + x0c) * 32,
                        gbase + (y1c * Wl + x1c) * 32);
    const float w = s.x;
    tws[t] = make_float4(w * wy0 * wx0 * yv0 * xv0,
                         w * wy0 * wx1 * yv0 * xv1,
                         w * wy1 * wx0 * yv1 * xv0,
                         w * wy1 * wx1 * yv1 * xv1);
  }
  __syncthreads();

  const int dq = t & 3, h = (t >> 2) & 7, pt = t >> 5;
  float a[8];
  {
    const float4* bb = (const float4*)(embed_b + l * 32 + dq * 8);
    const float4 b0 = bb[0], b1 = bb[1];
    a[0] = b0.x; a[1] = b0.y; a[2] = b0.z; a[3] = b0.w;
    a[4] = b1.x; a[5] = b1.y; a[6] = b1.z; a[7] = b1.w;
  }
  #pragma unroll
  for (int s = 0; s < 4; ++s) {
    const int slot = pt * 32 + h * 4 + s;
    const int4   o = tofs[slot];
    const float4 w = tws[slot];
    const half8 v00 = *(const half8*)(g16 + o.x + dq * 8);
    const half8 v01 = *(const half8*)(g16 + o.y + dq * 8);
    const half8 v10 = *(const half8*)(g16 + o.z + dq * 8);
    const half8 v11 = *(const half8*)(g16 + o.w + dq * 8);
    #pragma unroll
    for (int j = 0; j < 8; ++j)
      a[j] += w.x * (float)v00[j] + w.y * (float)v01[j]
            + w.z * (float)v10[j] + w.w * (float)v11[j];
  }
  float* od = out + (size_t)(gp0 + pt) * 256 + h * 32 + dq * 8;
  ((float4*)od)[0] = make_float4(a[0], a[1], a[2], a[3]);
  ((float4*)od)[1] = make_float4(a[4], a[5], a[6], a[7]);
}

// ---------------------------------------------------------------------------
extern "C" void kernel_launch(void* const* d_in, const int* in_sizes, int n_in,
                              void* d_out, int out_size, void* d_ws, size_t ws_size,
                              hipStream_t stream) {
  const float* x      = (const float*)d_in[0];
  const float* ref    = (const float*)d_in[1];
  const float* w_attn = (const float*)d_in[6];
  const float* b_attn = (const float*)d_in[7];
  const float* w_off  = (const float*)d_in[8];
  const float* b_off  = (const float*)d_in[9];
  const float* emb_w  = (const float*)d_in[10];
  const float* emb_b  = (const float*)d_in[11];
  float* ws  = (float*)d_ws;
  float* out = (float*)d_out;

  _Float16* g16   = (_Float16*)(ws + G_F);
  float4*   samp4 = (float4*)(ws + SAMP_F);
  _Float16* WuT   = (_Float16*)(ws + WU_F);
  _Float16* ET16  = (_Float16*)(ws + ET_F);

  k0_conv<<<128, 256, 0, stream>>>(w_attn, w_off, emb_w, WuT, ET16);

  stage1<<<NG_GPROJ + B_ * L_ * P_ / 64, 256, 0, stream>>>(
      (const float*)d_in[2], (const float*)d_in[3],
      (const float*)d_in[4], (const float*)d_in[5], ET16, g16,
      x, ref, WuT, b_attn, b_off, samp4);

  k3_main<<<B_ * L_ * P_ / 8, 256, 0, stream>>>(g16, samp4, emb_b, out);
}

// Round 16
// 52.999 us; speedup vs baseline: 1.1624x; 1.1624x over previous
//
#include <hip/hip_runtime.h>
#include <math.h>

#define B_   8
#define L_   4
#define P_   1024
#define C_   256
#define NH_  8
#define NS_  4
#define HD_  32

typedef _Float16 half8 __attribute__((ext_vector_type(8)));
typedef float    f32x4 __attribute__((ext_vector_type(4)));

// ws layout (float offsets)
#define G_F     0u          // projected maps fp16: 1,392,640 halves
#define SAMP_F  1392640u    // per-sample (w,fx,fy,0) float4: 32768*32*4 floats
#define WU_F    5586944u    // WuB fp16 fragment-major: 24576 halves
#define ET_F    5611520u    // embed_w fp16 e-major (4,32,256): 32768 halves

__constant__ const int kGoff[4] = {0, 1048576, 1310720, 1376256};  // half units

#define XH2 72              // smx padded half stride (144 B)
#define LGS 100             // logits row stride (floats)
#define FTS 40              // flT padded half stride (80 B)
#define NG_GPROJ 680        // 8 batches * 85 tiles

// ---------------------------------------------------------------------------
// k0: WuB fp16 fragment-major [((f*6+nt)*64+lane)*8+i]  +  ET16 (4,32,256)
// ---------------------------------------------------------------------------
__global__ void k0_conv(const float* __restrict__ wa, const float* __restrict__ wo,
                        const float* __restrict__ embed_w,
                        _Float16* __restrict__ WuB, _Float16* __restrict__ ET16) {
  const int bx = blockIdx.x, t = threadIdx.x;
  if (bx < 96) {
    const int n = bx, c = t;
    const float v = (n < 32) ? wa[c * 32 + n] : wo[c * 64 + (n - 32)];
    const int f = c >> 5, kgw = (c >> 3) & 3, i = c & 7;
    const int nt = n >> 4, lr = n & 15;
    WuB[(((f * 6 + nt) * 64) + kgw * 16 + lr) * 8 + i] = (_Float16)v;
  } else {
    // embed: src (l, c, 32e), dst (l, e, 256c)
    const int i0 = (bx - 96) * 1024 + t * 4;
    const int l = i0 >> 13, rem = i0 & 8191;
    const int c = rem >> 5, e0 = rem & 31;
    const float4 v = *(const float4*)(embed_w + i0);
    _Float16* d = ET16 + l * 8192 + c;
    d[(e0 + 0) * 256] = (_Float16)v.x;
    d[(e0 + 1) * 256] = (_Float16)v.y;
    d[(e0 + 2) * 256] = (_Float16)v.z;
    d[(e0 + 3) * 256] = (_Float16)v.w;
  }
}

// ---------------------------------------------------------------------------
// stage1: horizontal fusion.
//   blocks [0, 680):   gproj via MFMA; flT dbuf; ET16 B-frags from L2;
//                      feat loads 2-deep pipelined. 1 barrier/chunk.
//   blocks [680,1192): k2 MFMA GEMM; x staged (smx dbuf, 1 barrier/chunk);
//                      B-frags DIRECT from fragment-major WuB (1KB/inst, L2).
// ---------------------------------------------------------------------------
__global__ __launch_bounds__(256) void stage1(
    const float* __restrict__ f0, const float* __restrict__ f1,
    const float* __restrict__ f2, const float* __restrict__ f3,
    const _Float16* __restrict__ ET16, _Float16* __restrict__ g16,
    const float* __restrict__ x,    // (32768, 256)
    const float* __restrict__ ref,  // (32768, 2)
    const _Float16* __restrict__ WuB,
    const float* __restrict__ ba, const float* __restrict__ bo,
    float4* __restrict__ samp4)     // (32768, 32)
{
  __shared__ float4 smraw4[1600];   // 25600 B
  const int t = threadIdx.x;
  const int bx = blockIdx.x;
  const int lane = t & 63, wv = t >> 6;
  const int lr = lane & 15, kg = lane >> 4;

  if (bx < NG_GPROJ) {
    // ========== gproj path: flT dbuf 10 KB, ET from L2 ==========
    _Float16* flT = (_Float16*)smraw4;        // 2 x [64][FTS]
    const int b = bx / 85;
    int sub = bx - b * 85, l, tile;
    const float* src;
    if (sub < 64)      { l = 0; tile = sub;      src = f0; }
    else if (sub < 80) { l = 1; tile = sub - 64; src = f1; }
    else if (sub < 84) { l = 2; tile = sub - 80; src = f2; }
    else               { l = 3; tile = 0;        src = f3; }
    const int Wl = 64 >> l, S = Wl * Wl;
    const int s0 = tile * 64;

    const float* sb = src + (size_t)b * C_ * S + s0;
    const _Float16* ETl = ET16 + (size_t)l * 8192;
    const int sl = t & 63, cb = (t >> 6) * 8;

    float vcur[8], vnext[8];
    #pragma unroll
    for (int i = 0; i < 8; ++i) vnext[i] = sb[(size_t)(cb + i) * S + sl];

    f32x4 acc0 = (f32x4){0.f, 0.f, 0.f, 0.f};
    f32x4 acc1 = (f32x4){0.f, 0.f, 0.f, 0.f};

    #pragma unroll
    for (int c = 0; c < 8; ++c) {
      const int c0 = c * 32;
      #pragma unroll
      for (int i = 0; i < 8; ++i) vcur[i] = vnext[i];
      if (c < 7) {
        #pragma unroll
        for (int i = 0; i < 8; ++i)
          vnext[i] = sb[(size_t)(c0 + 32 + cb + i) * S + sl];
      }
      _Float16* fb = flT + (c & 1) * (64 * FTS);
      const half8 hv = {(_Float16)vcur[0], (_Float16)vcur[1], (_Float16)vcur[2], (_Float16)vcur[3],
                        (_Float16)vcur[4], (_Float16)vcur[5], (_Float16)vcur[6], (_Float16)vcur[7]};
      *(half8*)(fb + sl * FTS + cb) = hv;
      __syncthreads();
      const half8 a  = *(const half8*)(fb + (wv * 16 + lr) * FTS + kg * 8);
      const half8 b0 = *(const half8*)(ETl + (size_t)lr * 256 + c0 + kg * 8);
      const half8 b1 = *(const half8*)(ETl + (size_t)(16 + lr) * 256 + c0 + kg * 8);
      acc0 = __builtin_amdgcn_mfma_f32_16x16x32_f16(a, b0, acc0, 0, 0, 0);
      acc1 = __builtin_amdgcn_mfma_f32_16x16x32_f16(a, b1, acc1, 0, 0, 0);
    }

    _Float16* gb = g16 + kGoff[l] + ((size_t)b * S + s0 + wv * 16 + kg * 4) * 32;
    #pragma unroll
    for (int r = 0; r < 4; ++r) {
      gb[r * 32 + lr]      = (_Float16)acc0[r];
      gb[r * 32 + 16 + lr] = (_Float16)acc1[r];
    }
    return;
  }

  // ========== k2 path: smx dbuf + fragment-major B from L2 ==========
  _Float16* smx = (_Float16*)smraw4;             // 2 x [64][XH2] = 18432 B
  float*    lg  = (float*)smraw4;                // [64][LGS] (reuse after GEMM)

  const int blk = bx - NG_GPROJ;                 // 0..511
  const int gp0 = blk * 64;

  f32x4 acc[6];
  #pragma unroll
  for (int nt = 0; nt < 6; ++nt) acc[nt] = (f32x4){0.f, 0.f, 0.f, 0.f};

  #pragma unroll
  for (int chunk = 0; chunk < 4; ++chunk) {
    const int c0 = chunk * 64;
    _Float16* sx = smx + (chunk & 1) * (64 * XH2);
    {
      const int pt = t >> 2, q = t & 3;
      const float4* src = (const float4*)(x + (size_t)(gp0 + pt) * 256 + c0 + q * 16);
      const float4 v0 = src[0], v1 = src[1], v2 = src[2], v3 = src[3];
      _Float16* dst = sx + pt * XH2 + q * 16;
      *(half8*)dst = (half8){(_Float16)v0.x, (_Float16)v0.y, (_Float16)v0.z, (_Float16)v0.w,
                             (_Float16)v1.x, (_Float16)v1.y, (_Float16)v1.z, (_Float16)v1.w};
      *(half8*)(dst + 8) = (half8){(_Float16)v2.x, (_Float16)v2.y, (_Float16)v2.z, (_Float16)v2.w,
                                   (_Float16)v3.x, (_Float16)v3.y, (_Float16)v3.z, (_Float16)v3.w};
    }
    __syncthreads();

    #pragma unroll
    for (int ks = 0; ks < 2; ++ks) {
      const int f = chunk * 2 + ks;
      const half8 a = *(const half8*)(sx + (wv * 16 + lr) * XH2 + ks * 32 + kg * 8);
      #pragma unroll
      for (int nt = 0; nt < 6; ++nt) {
        const half8 bf = *(const half8*)(WuB + (size_t)((f * 6 + nt) * 64 + lane) * 8);
        acc[nt] = __builtin_amdgcn_mfma_f32_16x16x32_f16(a, bf, acc[nt], 0, 0, 0);
      }
    }
  }
  __syncthreads();

  // spill logits (+bias): D col = lane&15 (n), row = kg*4+r (point)
  #pragma unroll
  for (int nt = 0; nt < 6; ++nt) {
    const int n = nt * 16 + lr;
    const float bv = (n < 32) ? ba[n] : bo[n - 32];
    #pragma unroll
    for (int r = 0; r < 4; ++r)
      lg[(wv * 16 + kg * 4 + r) * LGS + n] = acc[nt][r] + bv;
  }
  __syncthreads();

  // softmax + tanh + grid mapping -> samp4
  #pragma unroll
  for (int k = 0; k < 8; ++k) {
    const int slot = k * 256 + t;
    const int pp = slot >> 5, j = slot & 31;
    const int gp = gp0 + pp;
    const int l = (gp >> 10) & 3;
    const int Wl = 64 >> l;
    const float* lgp = lg + pp * LGS;
    const int h4 = (j >> 2) * 4;
    const float l0 = lgp[h4], l1 = lgp[h4 + 1], l2 = lgp[h4 + 2], l3 = lgp[h4 + 3];
    const float m = fmaxf(fmaxf(l0, l1), fmaxf(l2, l3));
    const float e0 = expf(l0 - m), e1 = expf(l1 - m), e2 = expf(l2 - m), e3 = expf(l3 - m);
    const float inv = 1.f / (e0 + e1 + e2 + e3);
    const float es[4] = {e0, e1, e2, e3};
    const float wj = es[j & 3] * inv;
    const float ox = tanhf(lgp[32 + 2 * j])     + ref[(size_t)gp * 2];
    const float oy = tanhf(lgp[32 + 2 * j + 1]) + ref[(size_t)gp * 2 + 1];
    const float sc = 0.5f * (float)(Wl - 1);
    samp4[(size_t)gp * 32 + j] = make_float4(wj, (ox + 1.f) * sc, (oy + 1.f) * sc, 0.f);
  }
}

// ---------------------------------------------------------------------------
// k3: 8 points/block (4096 blocks). Tap precompute -> fp16 gather -> out.
// ---------------------------------------------------------------------------
__global__ __launch_bounds__(256) void k3_main(
    const _Float16* __restrict__ g16,
    const float4* __restrict__ samp4,
    const float* __restrict__ embed_b,   // (L, 32)
    float* __restrict__ out)             // (32768, 256)
{
  __shared__ int4   tofs[256];
  __shared__ float4 tws[256];
  const int t = threadIdx.x, blk = blockIdx.x;   // 4096 blocks
  const int gp0 = blk * 8;
  const int l = (gp0 >> 10) & 3, b = gp0 >> 12;
  const int Wl = 64 >> l;
  const int gbase = kGoff[l] + b * Wl * Wl * 32;  // half units

  {
    const float4 s = samp4[(size_t)gp0 * 32 + t];
    const float fx = s.y, fy = s.z;
    const float x0f = floorf(fx), y0f = floorf(fy);
    const int x0 = (int)x0f, y0 = (int)y0f, x1 = x0 + 1, y1 = y0 + 1;
    const float wx1 = fx - x0f, wy1 = fy - y0f;
    const float wx0 = 1.f - wx1, wy0 = 1.f - wy1;
    const float xv0 = (x0 >= 0 && x0 < Wl) ? 1.f : 0.f;
    const float xv1 = (x1 >= 0 && x1 < Wl) ? 1.f : 0.f;
    const float yv0 = (y0 >= 0 && y0 < Wl) ? 1.f : 0.f;
    const float yv1 = (y1 >= 0 && y1 < Wl) ? 1.f : 0.f;
    const int x0c = min(max(x0, 0), Wl - 1), x1c = min(max(x1, 0), Wl - 1);
    const int y0c = min(max(y0, 0), Wl - 1), y1c = min(max(y1, 0), Wl - 1);
    tofs[t] = make_int4(gbase + (y0c * Wl + x0c) * 32,
                        gbase + (y0c * Wl + x1c) * 32,
                        gbase + (y1c * Wl + x0c) * 32,
                        gbase + (y1c * Wl + x1c) * 32);
    const float w = s.x;
    tws[t] = make_float4(w * wy0 * wx0 * yv0 * xv0,
                         w * wy0 * wx1 * yv0 * xv1,
                         w * wy1 * wx0 * yv1 * xv0,
                         w * wy1 * wx1 * yv1 * xv1);
  }
  __syncthreads();

  const int dq = t & 3, h = (t >> 2) & 7, pt = t >> 5;
  float a[8];
  {
    const float4* bb = (const float4*)(embed_b + l * 32 + dq * 8);
    const float4 b0 = bb[0], b1 = bb[1];
    a[0] = b0.x; a[1] = b0.y; a[2] = b0.z; a[3] = b0.w;
    a[4] = b1.x; a[5] = b1.y; a[6] = b1.z; a[7] = b1.w;
  }
  #pragma unroll
  for (int s = 0; s < 4; ++s) {
    const int slot = pt * 32 + h * 4 + s;
    const int4   o = tofs[slot];
    const float4 w = tws[slot];
    const half8 v00 = *(const half8*)(g16 + o.x + dq * 8);
    const half8 v01 = *(const half8*)(g16 + o.y + dq * 8);
    const half8 v10 = *(const half8*)(g16 + o.z + dq * 8);
    const half8 v11 = *(const half8*)(g16 + o.w + dq * 8);
    #pragma unroll
    for (int j = 0; j < 8; ++j)
      a[j] += w.x * (float)v00[j] + w.y * (float)v01[j]
            + w.z * (float)v10[j] + w.w * (float)v11[j];
  }
  float* od = out + (size_t)(gp0 + pt) * 256 + h * 32 + dq * 8;
  ((float4*)od)[0] = make_float4(a[0], a[1], a[2], a[3]);
  ((float4*)od)[1] = make_float4(a[4], a[5], a[6], a[7]);
}

// ---------------------------------------------------------------------------
extern "C" void kernel_launch(void* const* d_in, const int* in_sizes, int n_in,
                              void* d_out, int out_size, void* d_ws, size_t ws_size,
                              hipStream_t stream) {
  const float* x      = (const float*)d_in[0];
  const float* ref    = (const float*)d_in[1];
  const float* w_attn = (const float*)d_in[6];
  const float* b_attn = (const float*)d_in[7];
  const float* w_off  = (const float*)d_in[8];
  const float* b_off  = (const float*)d_in[9];
  const float* emb_w  = (const float*)d_in[10];
  const float* emb_b  = (const float*)d_in[11];
  float* ws  = (float*)d_ws;
  float* out = (float*)d_out;

  _Float16* g16   = (_Float16*)(ws + G_F);
  float4*   samp4 = (float4*)(ws + SAMP_F);
  _Float16* WuB   = (_Float16*)(ws + WU_F);
  _Float16* ET16  = (_Float16*)(ws + ET_F);

  k0_conv<<<128, 256, 0, stream>>>(w_attn, w_off, emb_w, WuB, ET16);

  stage1<<<NG_GPROJ + B_ * L_ * P_ / 64, 256, 0, stream>>>(
      (const float*)d_in[2], (const float*)d_in[3],
      (const float*)d_in[4], (const float*)d_in[5], ET16, g16,
      x, ref, WuB, b_attn, b_off, samp4);

  k3_main<<<B_ * L_ * P_ / 8, 256, 0, stream>>>(g16, samp4, emb_b, out);
}

// Round 17
// 50.586 us; speedup vs baseline: 1.2178x; 1.0477x over previous
//
#include <hip/hip_runtime.h>
#include <math.h>

#define B_   8
#define L_   4
#define P_   1024
#define C_   256
#define NH_  8
#define NS_  4
#define HD_  32

typedef _Float16 half8 __attribute__((ext_vector_type(8)));
typedef float    f32x4 __attribute__((ext_vector_type(4)));

// ws layout (float offsets)
#define G_F     0u          // projected maps fp16: 1,392,640 halves
#define SAMP_F  1392640u    // per-sample (w,fx,fy,0) float4: 32768*32*4 floats
#define WU_F    5586944u    // WuT fp16 (96,256): 24576 halves
#define ET_F    5611520u    // embed_w fp16 e-major (4,32,256): 32768 halves

__constant__ const int kGoff[4] = {0, 1048576, 1310720, 1376256};  // half units

#define XH2 72              // k2 smx/smw padded half stride (144 B)
#define LGS 100             // logits row stride (floats)
#define NG_GPROJ 680        // 8 batches * 85 tiles

// ---------------------------------------------------------------------------
// k0: WuT fp16 (96,256) K-major  +  ET16 fp16 (4,32,256) e-major
// ---------------------------------------------------------------------------
__global__ void k0_conv(const float* __restrict__ wa, const float* __restrict__ wo,
                        const float* __restrict__ embed_w,
                        _Float16* __restrict__ WuT, _Float16* __restrict__ ET16) {
  const int bx = blockIdx.x, t = threadIdx.x;
  if (bx < 96) {
    const int n = bx;
    const float v = (n < 32) ? wa[t * 32 + n] : wo[t * 64 + (n - 32)];
    WuT[n * 256 + t] = (_Float16)v;
  } else {
    // embed: src (l, c, 32e), dst (l, e, 256c)
    const int i0 = (bx - 96) * 1024 + t * 4;
    const int l = i0 >> 13, rem = i0 & 8191;
    const int c = rem >> 5, e0 = rem & 31;
    const float4 v = *(const float4*)(embed_w + i0);
    _Float16* d = ET16 + l * 8192 + c;
    d[(e0 + 0) * 256] = (_Float16)v.x;
    d[(e0 + 1) * 256] = (_Float16)v.y;
    d[(e0 + 2) * 256] = (_Float16)v.z;
    d[(e0 + 3) * 256] = (_Float16)v.w;
  }
}

// ---------------------------------------------------------------------------
// stage1: horizontal fusion.
//   blocks [0, 680):   gproj via MFMA — ZERO LDS, ZERO barriers: A-frags
//                      gathered per-lane direct from feat (64B segments),
//                      B-frags from L2-hot ET16, 2-deep channel prefetch.
//   blocks [680,1192): k2 MFMA GEMM, LDS-staged (R14 form) + softmax/tanh.
// ---------------------------------------------------------------------------
__global__ __launch_bounds__(256) void stage1(
    const float* __restrict__ f0, const float* __restrict__ f1,
    const float* __restrict__ f2, const float* __restrict__ f3,
    const _Float16* __restrict__ ET16, _Float16* __restrict__ g16,
    const float* __restrict__ x,    // (32768, 256)
    const float* __restrict__ ref,  // (32768, 2)
    const _Float16* __restrict__ WuT,
    const float* __restrict__ ba, const float* __restrict__ bo,
    float4* __restrict__ samp4)     // (32768, 32)
{
  __shared__ float4 smraw4[1600];   // 25600 B
  const int t = threadIdx.x;
  const int bx = blockIdx.x;
  const int lane = t & 63, wv = t >> 6;
  const int lr = lane & 15, kg = lane >> 4;

  if (bx < NG_GPROJ) {
    // ========== gproj path: no LDS, no barriers ==========
    const int b = bx / 85;
    int sub = bx - b * 85, l, tile;
    const float* src;
    if (sub < 64)      { l = 0; tile = sub;      src = f0; }
    else if (sub < 80) { l = 1; tile = sub - 64; src = f1; }
    else if (sub < 84) { l = 2; tile = sub - 80; src = f2; }
    else               { l = 3; tile = 0;        src = f3; }
    const int Wl = 64 >> l, S = Wl * Wl;
    const int s0 = tile * 64;
    const int srow = s0 + wv * 16 + lr;          // this lane's M row

    const float* sb = src + (size_t)b * C_ * S + srow;  // + c*S walks channels
    const _Float16* ETl = ET16 + (size_t)l * 8192;

    f32x4 acc0 = (f32x4){0.f, 0.f, 0.f, 0.f};
    f32x4 acc1 = (f32x4){0.f, 0.f, 0.f, 0.f};

    float vc[8], vn[8];
    #pragma unroll
    for (int i = 0; i < 8; ++i) vn[i] = sb[(size_t)(kg * 8 + i) * S];

    #pragma unroll
    for (int c = 0; c < 8; ++c) {
      const int c0 = c * 32;
      #pragma unroll
      for (int i = 0; i < 8; ++i) vc[i] = vn[i];
      if (c < 7) {
        #pragma unroll
        for (int i = 0; i < 8; ++i)
          vn[i] = sb[(size_t)(c0 + 32 + kg * 8 + i) * S];
      }
      const half8 a = {(_Float16)vc[0], (_Float16)vc[1], (_Float16)vc[2], (_Float16)vc[3],
                       (_Float16)vc[4], (_Float16)vc[5], (_Float16)vc[6], (_Float16)vc[7]};
      const half8 b0 = *(const half8*)(ETl + (size_t)lr * 256 + c0 + kg * 8);
      const half8 b1 = *(const half8*)(ETl + (size_t)(16 + lr) * 256 + c0 + kg * 8);
      acc0 = __builtin_amdgcn_mfma_f32_16x16x32_f16(a, b0, acc0, 0, 0, 0);
      acc1 = __builtin_amdgcn_mfma_f32_16x16x32_f16(a, b1, acc1, 0, 0, 0);
    }

    // D: row (s_local) = kg*4+r, col (e) = {lr, 16+lr}
    _Float16* gb = g16 + kGoff[l] + ((size_t)b * S + s0 + wv * 16 + kg * 4) * 32;
    #pragma unroll
    for (int r = 0; r < 4; ++r) {
      gb[r * 32 + lr]      = (_Float16)acc0[r];
      gb[r * 32 + 16 + lr] = (_Float16)acc1[r];
    }
    return;
  }

  // ========== k2 path (R14 form): LDS-staged MFMA GEMM ==========
  _Float16* smx = (_Float16*)smraw4;             // [64][XH2]
  _Float16* smw = (_Float16*)smraw4 + 64 * XH2;  // [96][XH2]
  float*    lg  = (float*)smraw4;                // [64][LGS] (reuse after GEMM)

  const int blk = bx - NG_GPROJ;                 // 0..511
  const int gp0 = blk * 64;

  f32x4 acc[6];
  #pragma unroll
  for (int nt = 0; nt < 6; ++nt) acc[nt] = (f32x4){0.f, 0.f, 0.f, 0.f};

  #pragma unroll
  for (int chunk = 0; chunk < 4; ++chunk) {
    const int c0 = chunk * 64;
    if (chunk) __syncthreads();
    {
      const int pt = t >> 2, q = t & 3;
      const float4* src = (const float4*)(x + (size_t)(gp0 + pt) * 256 + c0 + q * 16);
      const float4 v0 = src[0], v1 = src[1], v2 = src[2], v3 = src[3];
      _Float16* dst = smx + pt * XH2 + q * 16;
      *(half8*)dst = (half8){(_Float16)v0.x, (_Float16)v0.y, (_Float16)v0.z, (_Float16)v0.w,
                             (_Float16)v1.x, (_Float16)v1.y, (_Float16)v1.z, (_Float16)v1.w};
      *(half8*)(dst + 8) = (half8){(_Float16)v2.x, (_Float16)v2.y, (_Float16)v2.z, (_Float16)v2.w,
                                   (_Float16)v3.x, (_Float16)v3.y, (_Float16)v3.z, (_Float16)v3.w};
    }
    {
      #pragma unroll
      for (int q = 0; q < 3; ++q) {
        const int idx = q * 256 + t;
        const int n = idx >> 3, col8 = idx & 7;
        *(float4*)(smw + n * XH2 + col8 * 8) =
            *(const float4*)(WuT + (size_t)n * 256 + c0 + col8 * 8);
      }
    }
    __syncthreads();

    #pragma unroll
    for (int ks = 0; ks < 2; ++ks) {
      const half8 a = *(const half8*)(smx + (wv * 16 + lr) * XH2 + ks * 32 + kg * 8);
      #pragma unroll
      for (int nt = 0; nt < 6; ++nt) {
        const half8 bf = *(const half8*)(smw + (nt * 16 + lr) * XH2 + ks * 32 + kg * 8);
        acc[nt] = __builtin_amdgcn_mfma_f32_16x16x32_f16(a, bf, acc[nt], 0, 0, 0);
      }
    }
  }
  __syncthreads();

  #pragma unroll
  for (int nt = 0; nt < 6; ++nt) {
    const int n = nt * 16 + lr;
    const float bv = (n < 32) ? ba[n] : bo[n - 32];
    #pragma unroll
    for (int r = 0; r < 4; ++r)
      lg[(wv * 16 + kg * 4 + r) * LGS + n] = acc[nt][r] + bv;
  }
  __syncthreads();

  #pragma unroll
  for (int k = 0; k < 8; ++k) {
    const int slot = k * 256 + t;
    const int pp = slot >> 5, j = slot & 31;
    const int gp = gp0 + pp;
    const int l = (gp >> 10) & 3;
    const int Wl = 64 >> l;
    const float* lgp = lg + pp * LGS;
    const int h4 = (j >> 2) * 4;
    const float l0 = lgp[h4], l1 = lgp[h4 + 1], l2 = lgp[h4 + 2], l3 = lgp[h4 + 3];
    const float m = fmaxf(fmaxf(l0, l1), fmaxf(l2, l3));
    const float e0 = expf(l0 - m), e1 = expf(l1 - m), e2 = expf(l2 - m), e3 = expf(l3 - m);
    const float inv = 1.f / (e0 + e1 + e2 + e3);
    const float es[4] = {e0, e1, e2, e3};
    const float wj = es[j & 3] * inv;
    const float ox = tanhf(lgp[32 + 2 * j])     + ref[(size_t)gp * 2];
    const float oy = tanhf(lgp[32 + 2 * j + 1]) + ref[(size_t)gp * 2 + 1];
    const float sc = 0.5f * (float)(Wl - 1);
    samp4[(size_t)gp * 32 + j] = make_float4(wj, (ox + 1.f) * sc, (oy + 1.f) * sc, 0.f);
  }
}

// ---------------------------------------------------------------------------
// k3: 8 points/block (4096 blocks). Tap precompute -> fp16 gather -> out.
// ---------------------------------------------------------------------------
__global__ __launch_bounds__(256) void k3_main(
    const _Float16* __restrict__ g16,
    const float4* __restrict__ samp4,
    const float* __restrict__ embed_b,   // (L, 32)
    float* __restrict__ out)             // (32768, 256)
{
  __shared__ int4   tofs[256];
  __shared__ float4 tws[256];
  const int t = threadIdx.x, blk = blockIdx.x;   // 4096 blocks
  const int gp0 = blk * 8;
  const int l = (gp0 >> 10) & 3, b = gp0 >> 12;
  const int Wl = 64 >> l;
  const int gbase = kGoff[l] + b * Wl * Wl * 32;  // half units

  {
    const float4 s = samp4[(size_t)gp0 * 32 + t];
    const float fx = s.y, fy = s.z;
    const float x0f = floorf(fx), y0f = floorf(fy);
    const int x0 = (int)x0f, y0 = (int)y0f, x1 = x0 + 1, y1 = y0 + 1;
    const float wx1 = fx - x0f, wy1 = fy - y0f;
    const float wx0 = 1.f - wx1, wy0 = 1.f - wy1;
    const float xv0 = (x0 >= 0 && x0 < Wl) ? 1.f : 0.f;
    const float xv1 = (x1 >= 0 && x1 < Wl) ? 1.f : 0.f;
    const float yv0 = (y0 >= 0 && y0 < Wl) ? 1.f : 0.f;
    const float yv1 = (y1 >= 0 && y1 < Wl) ? 1.f : 0.f;
    const int x0c = min(max(x0, 0), Wl - 1), x1c = min(max(x1, 0), Wl - 1);
    const int y0c = min(max(y0, 0), Wl - 1), y1c = min(max(y1, 0), Wl - 1);
    tofs[t] = make_int4(gbase + (y0c * Wl + x0c) * 32,
                        gbase + (y0c * Wl + x1c) * 32,
                        gbase + (y1c * Wl + x0c) * 32,
                        gbase + (y1c * Wl + x1c) * 32);
    const float w = s.x;
    tws[t] = make_float4(w * wy0 * wx0 * yv0 * xv0,
                         w * wy0 * wx1 * yv0 * xv1,
                         w * wy1 * wx0 * yv1 * xv0,
                         w * wy1 * wx1 * yv1 * xv1);
  }
  __syncthreads();

  const int dq = t & 3, h = (t >> 2) & 7, pt = t >> 5;
  float a[8];
  {
    const float4* bb = (const float4*)(embed_b + l * 32 + dq * 8);
    const float4 b0 = bb[0], b1 = bb[1];
    a[0] = b0.x; a[1] = b0.y; a[2] = b0.z; a[3] = b0.w;
    a[4] = b1.x; a[5] = b1.y; a[6] = b1.z; a[7] = b1.w;
  }
  #pragma unroll
  for (int s = 0; s < 4; ++s) {
    const int slot = pt * 32 + h * 4 + s;
    const int4   o = tofs[slot];
    const float4 w = tws[slot];
    const half8 v00 = *(const half8*)(g16 + o.x + dq * 8);
    const half8 v01 = *(const half8*)(g16 + o.y + dq * 8);
    const half8 v10 = *(const half8*)(g16 + o.z + dq * 8);
    const half8 v11 = *(const half8*)(g16 + o.w + dq * 8);
    #pragma unroll
    for (int j = 0; j < 8; ++j)
      a[j] += w.x * (float)v00[j] + w.y * (float)v01[j]
            + w.z * (float)v10[j] + w.w * (float)v11[j];
  }
  float* od = out + (size_t)(gp0 + pt) * 256 + h * 32 + dq * 8;
  ((float4*)od)[0] = make_float4(a[0], a[1], a[2], a[3]);
  ((float4*)od)[1] = make_float4(a[4], a[5], a[6], a[7]);
}

// ---------------------------------------------------------------------------
extern "C" void kernel_launch(void* const* d_in, const int* in_sizes, int n_in,
                              void* d_out, int out_size, void* d_ws, size_t ws_size,
                              hipStream_t stream) {
  const float* x      = (const float*)d_in[0];
  const float* ref    = (const float*)d_in[1];
  const float* w_attn = (const float*)d_in[6];
  const float* b_attn = (const float*)d_in[7];
  const float* w_off  = (const float*)d_in[8];
  const float* b_off  = (const float*)d_in[9];
  const float* emb_w  = (const float*)d_in[10];
  const float* emb_b  = (const float*)d_in[11];
  float* ws  = (float*)d_ws;
  float* out = (float*)d_out;

  _Float16* g16   = (_Float16*)(ws + G_F);
  float4*   samp4 = (float4*)(ws + SAMP_F);
  _Float16* WuT   = (_Float16*)(ws + WU_F);
  _Float16* ET16  = (_Float16*)(ws + ET_F);

  k0_conv<<<128, 256, 0, stream>>>(w_attn, w_off, emb_w, WuT, ET16);

  stage1<<<NG_GPROJ + B_ * L_ * P_ / 64, 256, 0, stream>>>(
      (const float*)d_in[2], (const float*)d_in[3],
      (const float*)d_in[4], (const float*)d_in[5], ET16, g16,
      x, ref, WuT, b_attn, b_off, samp4);

  k3_main<<<B_ * L_ * P_ / 8, 256, 0, stream>>>(g16, samp4, emb_b, out);
}